// Round 12
// baseline (1122.146 us; speedup 1.0000x reference)
//
#include <hip/hip_runtime.h>
#include <hip/hip_bf16.h>

#define IN_F 4096
#define OUT_F 11008

typedef __bf16 bf16_t;
typedef bf16_t bf16x8 __attribute__((ext_vector_type(8)));
typedef float f32x4 __attribute__((ext_vector_type(4)));
typedef unsigned int u32;

// ============================ pass 1a: x f32 -> bf16 ============================
__global__ __launch_bounds__(256) void cvt_x_kernel(const float* __restrict__ x,
                                                    bf16_t* __restrict__ xb) {
    size_t i = ((size_t)blockIdx.x * 256 + threadIdx.x) * 8;
    f32x4 v0 = __builtin_nontemporal_load((const f32x4*)(x + i));
    f32x4 v1 = __builtin_nontemporal_load((const f32x4*)(x + i + 4));
    bf16x8 h;
    h[0]=(bf16_t)v0[0]; h[1]=(bf16_t)v0[1]; h[2]=(bf16_t)v0[2]; h[3]=(bf16_t)v0[3];
    h[4]=(bf16_t)v1[0]; h[5]=(bf16_t)v1[1]; h[6]=(bf16_t)v1[2]; h[7]=(bf16_t)v1[3];
    *(bf16x8*)(xb + i) = h;
}

// ============ pass 2: 256x256 8-phase GEMM with in-register B dequant ============
// R11: B never touches LDS. The 16x16x32 B-fragment (8 consecutive k at one
// col) == one qweight u32 (8 nibbles): each lane loads its u32 and dequants
// in-register (~28 VALU/frag, on the idle VALU pipe). Removes B LDS reads,
// B staging, the dequant prepass, and 90MB of ws traffic. A-side keeps R8's
// verified ring (stages ph1/ph4/ph5/ph8, VMCNT2@ph4, VMCNT2@ph8).
// Dequants run one phase ahead of consumption; w-loads 3 phases ahead;
// per-group scales double-buffered (load raws ph6, convert ph7).

#define NI (IN_F / 128)   // 32 iterations = 32 groups, 64 K-tiles

__global__ __launch_bounds__(512, 2) void gemm_dq(const bf16_t* __restrict__ A,
                                                  const int* __restrict__ qweight,
                                                  const float* __restrict__ scales,
                                                  const int* __restrict__ qzeros,
                                                  float* __restrict__ C) {
    __shared__ __align__(16) bf16_t smemA[2 * 2 * 128 * 64];   // 64 KiB (A only)

    const int tid  = threadIdx.x;
    const int lane = tid & 63;
    const int wid  = tid >> 6;      // 0..7
    const int wr   = wid >> 2;      // 0..1  (M half)
    const int wc   = wid & 3;       // 0..3  (N quarter)

    // bijective XCD swizzle: nwg = 1376 = 8*172
    const int bid = blockIdx.x;
    const int swz = (bid & 7) * 172 + (bid >> 3);
    const int bx = swz % 43;
    const int by = swz / 43;
    const int m0 = by * 256;
    const int n0 = bx * 256;

    // A staging map: linear LDS slot -> inverse-swizzled global position
    int lr0, kb0, lr1, kb1;
    {
        int L0 = tid * 16;
        int p0 = L0 ^ (((L0 >> 7) & 7) << 4);
        lr0 = p0 >> 7; kb0 = (p0 & 127) >> 1;
        int L1 = (512 + tid) * 16;
        int p1 = L1 ^ (((L1 >> 7) & 7) << 4);
        lr1 = p1 >> 7; kb1 = (p1 & 127) >> 1;
    }

    // A fragment-read swizzled column byte offsets within a 128B row
    const int xm = (lane & 7) << 4;
    const int arow = lane & 15;
    int colk[2];
    #pragma unroll
    for (int ks = 0; ks < 2; ++ks)
        colk[ks] = ((ks * 64) + ((lane >> 4) * 16)) ^ xm;

    // B-side per-lane pointers (col = n0 + wc*64 + nt*16 + (lane&15))
    const int ncol = n0 + wc * 64 + (lane & 15);
    const int* qwp = qweight + (size_t)(lane >> 4) * OUT_F + ncol;
    const float* sp = scales + ncol;                 // + g*OUT_F + nt*16
    const int*   zp = qzeros + (ncol >> 3);          // + g*(OUT_F/8) + nt*2
    const int    zsh = (lane & 7) * 4;

#define STAGE_A(buf, half, koff)                                                           \
    do {                                                                                   \
        const bf16_t* g0_ = A + (size_t)(m0 + (half) * 128 + lr0) * IN_F + (koff) + kb0;   \
        __builtin_amdgcn_global_load_lds(                                                  \
            (const __attribute__((address_space(1))) u32*)g0_,                             \
            (__attribute__((address_space(3))) u32*)((char*)smemA + (buf) * 32768 +        \
                                                     (half) * 16384 + wid * 1024),         \
            16, 0, 0);                                                                     \
        const bf16_t* g1_ = A + (size_t)(m0 + (half) * 128 + lr1) * IN_F + (koff) + kb1;   \
        __builtin_amdgcn_global_load_lds(                                                  \
            (const __attribute__((address_space(1))) u32*)g1_,                             \
            (__attribute__((address_space(3))) u32*)((char*)smemA + (buf) * 32768 +        \
                                                     (half) * 16384 + 8192 + wid * 1024),  \
            16, 0, 0);                                                                     \
    } while (0)

// 8 ds_read_b128 -> aR : A fragments (4 m-tiles x 2 k-slices)
#define RD_A(dst, buf, mbase)                                                              \
    _Pragma("unroll") for (int mm = 0; mm < 4; ++mm)                                       \
    _Pragma("unroll") for (int ks = 0; ks < 2; ++ks)                                       \
        dst[mm * 2 + ks] = *(const bf16x8*)((const char*)smemA + (buf) * 32768 +           \
            wr * 16384 + (((mbase) + mm) * 16 + arow) * 128 + colk[ks]);

// 8 global u32: w[nt*2+ks] = qweight[kwbase + rowoff + ks*4 + (lane>>4)][ncol + nt*16]
#define LOAD_W(dst, rowoff)                                                                \
    _Pragma("unroll") for (int nt = 0; nt < 4; ++nt)                                       \
    _Pragma("unroll") for (int ks = 0; ks < 2; ++ks)                                       \
        dst[nt * 2 + ks] = qwp[(size_t)((rowoff) + ks * 4) * OUT_F + nt * 16];

// dequant one B pair (n-tiles nt0, nt0+1; 2 k-slices) from w words
#define DEQ(dst, wArr, nt0)                                                                \
    _Pragma("unroll") for (int nn = 0; nn < 2; ++nn)                                       \
    _Pragma("unroll") for (int ks = 0; ks < 2; ++ks) {                                     \
        const int wv_ = wArr[((nt0) + nn) * 2 + ks];                                       \
        const float s_ = s0[(nt0) + nn];                                                   \
        const float z_ = nsz0[(nt0) + nn];                                                 \
        bf16x8 h_;                                                                         \
        _Pragma("unroll") for (int j = 0; j < 8; ++j)                                      \
            h_[j] = (bf16_t)fmaf((float)((wv_ >> (4 * j)) & 0xF), s_, z_);                 \
        dst[nn * 2 + ks] = h_;                                                             \
    }

// 16 MFMA: one quadrant (4 m x 2 n x 2 ks)
#define MFMA_Q(aArr, bArr, mbase, nbase)                                                   \
    __builtin_amdgcn_s_setprio(1);                                                         \
    _Pragma("unroll") for (int mm = 0; mm < 4; ++mm)                                       \
    _Pragma("unroll") for (int nn = 0; nn < 2; ++nn)                                       \
    _Pragma("unroll") for (int ks = 0; ks < 2; ++ks)                                       \
        acc[(mbase) + mm][(nbase) + nn] = __builtin_amdgcn_mfma_f32_16x16x32_bf16(         \
            aArr[mm * 2 + ks], bArr[nn * 2 + ks], acc[(mbase) + mm][(nbase) + nn],         \
            0, 0, 0);                                                                      \
    __builtin_amdgcn_s_setprio(0);

#define BAR() __builtin_amdgcn_s_barrier()
#define VMCNT2() asm volatile("s_waitcnt vmcnt(2)" ::: "memory")
#define VMCNT0() asm volatile("s_waitcnt vmcnt(0)" ::: "memory")

    f32x4 acc[8][4];
    #pragma unroll
    for (int m = 0; m < 8; ++m)
        #pragma unroll
        for (int n = 0; n < 4; ++n)
            acc[m][n] = (f32x4)0.0f;

    bf16x8 aR[8], b01[4], b23[4];
    int   w0[8], w1[8];
    float s0[4], nsz0[4];
    float sraw[4]; int zraw[4];

    // ---- prologue: group-0 scales, w0(T0), deq b01; stage T0 + T1-h0
    LOAD_W(w0, 0);
    #pragma unroll
    for (int nt = 0; nt < 4; ++nt) { sraw[nt] = sp[nt * 16]; zraw[nt] = zp[nt * 2]; }
    #pragma unroll
    for (int nt = 0; nt < 4; ++nt) {
        s0[nt] = sraw[nt];
        nsz0[nt] = -sraw[nt] * (float)(((zraw[nt] >> zsh) & 0xF) + 1);
    }
    DEQ(b01, w0, 0);
    STAGE_A(0, 0, 0); STAGE_A(0, 1, 0);
    STAGE_A(1, 0, 64);
    VMCNT2();          // T0's 4 loads landed; T1-h0's 2 in flight
    BAR();

    for (int i = 0; i < NI; ++i) {
        const int  kc = i * 128;        // T0 in buf0; T1 = kc+64 in buf1
        const int  kn = kc + 128;       // T2 in buf0; T3 = kn+64 in buf1
        const bool nl = (i + 1 < NI);

        // ph1: reads A(M0,buf0); stage A(1,1)(T1); deq b23(w0); MFMA(M0,N01)
        RD_A(aR, 0, 0);
        STAGE_A(1, 1, kc + 64);
        DEQ(b23, w0, 2);
        MFMA_Q(aR, b01, 0, 0);
        BAR();
        // ph2: issue w1 (T1 rows); MFMA(M0,N23)
        LOAD_W(w1, 8);
        MFMA_Q(aR, b23, 0, 2);
        BAR();
        // ph3: reads A(M1,buf0); MFMA(M1,N01)
        RD_A(aR, 0, 4);
        MFMA_Q(aR, b01, 4, 0);
        BAR();
        // ph4: stage A(0,0)(T2); deq b01(w1); MFMA(M1,N23); confirm T1
        if (nl) STAGE_A(0, 0, kn);
        DEQ(b01, w1, 0);
        MFMA_Q(aR, b23, 4, 2);
        if (nl) VMCNT2(); else VMCNT0();
        BAR();
        // ph5: reads A(M0,buf1); stage A(0,1)(T2); deq b23(w1); MFMA(M0,N01)
        RD_A(aR, 1, 0);
        if (nl) STAGE_A(0, 1, kn);
        DEQ(b23, w1, 2);
        MFMA_Q(aR, b01, 0, 0);
        BAR();
        // ph6: issue w0' (T2 rows) + next-group scale raws; MFMA(M0,N23)
        if (nl) {
            LOAD_W(w0, 16);
            #pragma unroll
            for (int nt = 0; nt < 4; ++nt) {
                sraw[nt] = sp[(size_t)(i + 1) * OUT_F + nt * 16];
                zraw[nt] = zp[(size_t)(i + 1) * (OUT_F / 8) + nt * 2];
            }
        }
        MFMA_Q(aR, b23, 0, 2);
        BAR();
        // ph7: reads A(M1,buf1); convert next-group scales; MFMA(M1,N01)
        RD_A(aR, 1, 4);
        if (nl) {
            #pragma unroll
            for (int nt = 0; nt < 4; ++nt) {
                s0[nt] = sraw[nt];
                nsz0[nt] = -sraw[nt] * (float)(((zraw[nt] >> zsh) & 0xF) + 1);
            }
        }
        MFMA_Q(aR, b01, 4, 0);
        BAR();
        // ph8: stage A(1,0)(T3); deq b01(w0',next group); MFMA(M1,N23); confirm T2
        if (nl) {
            STAGE_A(1, 0, kn + 64);
            DEQ(b01, w0, 0);
        }
        MFMA_Q(aR, b23, 4, 2);
        if (nl) VMCNT2();
        BAR();

        qwp += (size_t)16 * OUT_F;   // advance to next 128-k block of qweight
    }

    // epilogue: C/D layout col = lane&15, row = (lane>>4)*4 + r
    const int cn  = lane & 15;
    const int cr4 = (lane >> 4) * 4;
    #pragma unroll
    for (int m = 0; m < 8; ++m) {
        #pragma unroll
        for (int r = 0; r < 4; ++r) {
            const int grow = m0 + wr * 128 + m * 16 + cr4 + r;
            float* orow = C + (size_t)grow * OUT_F + n0 + wc * 64 + cn;
            #pragma unroll
            for (int n = 0; n < 4; ++n)
                orow[n * 16] = acc[m][n][r];
        }
    }
}

// ===================== fallback: fused kernel (R0 structure) =====================
#define BMf 128
#define BNf 128
#define BKf 32
#define LDPF 40

__global__ __launch_bounds__(256, 2) void gptq_gemm_fused(
    const float* __restrict__ x, const int* __restrict__ qweight,
    const float* __restrict__ scales, const int* __restrict__ qzeros,
    float* __restrict__ out)
{
    __shared__ bf16_t As[BMf * LDPF];
    __shared__ bf16_t Bs[BNf * LDPF];
    const int tid = threadIdx.x, lane = tid & 63, wid = tid >> 6;
    const int wr = wid >> 1, wc = wid & 1;
    const int m0 = blockIdx.y * BMf, n0 = blockIdx.x * BNf;
    const int a_row = tid >> 2, a_slot = tid & 3;
    const int b_k8l = tid >> 7, b_n = tid & 127;

    f32x4 acc[4][4];
    #pragma unroll
    for (int i = 0; i < 4; ++i)
        #pragma unroll
        for (int j = 0; j < 4; ++j) acc[i][j] = (f32x4)0.0f;

    for (int kt = 0; kt < IN_F / BKf; ++kt) {
        const int k0 = kt * BKf;
        const int g  = k0 >> 7;
        __syncthreads();
        #pragma unroll
        for (int p = 0; p < 2; ++p) {
            const int row = a_row + p * 64;
            const float* src = x + (size_t)(m0 + row) * IN_F + k0 + a_slot * 8;
            f32x4 v0 = *(const f32x4*)src;
            f32x4 v1 = *(const f32x4*)(src + 4);
            bf16x8 h;
            h[0]=(bf16_t)v0[0]; h[1]=(bf16_t)v0[1]; h[2]=(bf16_t)v0[2]; h[3]=(bf16_t)v0[3];
            h[4]=(bf16_t)v1[0]; h[5]=(bf16_t)v1[1]; h[6]=(bf16_t)v1[2]; h[7]=(bf16_t)v1[3];
            *(bf16x8*)(&As[row * LDPF + a_slot * 8]) = h;
        }
        {
            const int gn = n0 + b_n;
            const float s  = scales[(size_t)g * OUT_F + gn];
            const int   zw = qzeros[(size_t)g * (OUT_F / 8) + (gn >> 3)];
            const float sz = s * (float)(((zw >> ((gn & 7) * 4)) & 0xF) + 1);
            #pragma unroll
            for (int p = 0; p < 2; ++p) {
                const int k8l = b_k8l + p * 2;
                const int w = qweight[(size_t)(k0 / 8 + k8l) * OUT_F + gn];
                bf16x8 h;
                #pragma unroll
                for (int j = 0; j < 8; ++j)
                    h[j] = (bf16_t)fmaf((float)((w >> (4 * j)) & 0xF), s, -sz);
                *(bf16x8*)(&Bs[b_n * LDPF + k8l * 8]) = h;
            }
        }
        __syncthreads();
        bf16x8 af[4], bfr[4];
        #pragma unroll
        for (int m = 0; m < 4; ++m)
            af[m] = *(const bf16x8*)(&As[(wr * 64 + m * 16 + (lane & 15)) * LDPF + (lane >> 4) * 8]);
        #pragma unroll
        for (int n = 0; n < 4; ++n)
            bfr[n] = *(const bf16x8*)(&Bs[(wc * 64 + n * 16 + (lane & 15)) * LDPF + (lane >> 4) * 8]);
        #pragma unroll
        for (int m = 0; m < 4; ++m)
            #pragma unroll
            for (int n = 0; n < 4; ++n)
                acc[m][n] = __builtin_amdgcn_mfma_f32_16x16x32_bf16(af[m], bfr[n], acc[m][n], 0, 0, 0);
    }
    const int cn = lane & 15, cr4 = (lane >> 4) * 4;
    #pragma unroll
    for (int m = 0; m < 4; ++m)
        #pragma unroll
        for (int r = 0; r < 4; ++r) {
            const int grow = m0 + wr * 64 + m * 16 + cr4 + r;
            float* orow = out + (size_t)grow * OUT_F + n0 + wc * 64 + cn;
            #pragma unroll
            for (int n = 0; n < 4; ++n) orow[n * 16] = acc[m][n][r];
        }
}

extern "C" void kernel_launch(void* const* d_in, const int* in_sizes, int n_in,
                              void* d_out, int out_size, void* d_ws, size_t ws_size,
                              hipStream_t stream) {
    const float* x       = (const float*)d_in[0];
    const int*   qweight = (const int*)d_in[1];
    const float* scales  = (const float*)d_in[2];
    const int*   qzeros  = (const int*)d_in[3];
    float* out = (float*)d_out;

    const int M = in_sizes[0] / IN_F;                       // 8192
    const size_t xb_bytes = (size_t)M * IN_F * 2;           // 67 MB

    if (ws_size >= xb_bytes && (M % 256) == 0) {
        bf16_t* xb = (bf16_t*)d_ws;
        cvt_x_kernel<<<dim3((M * IN_F) / (256 * 8)), dim3(256), 0, stream>>>(x, xb);
        const int nwg = (OUT_F / 256) * (M / 256);          // 43*32 = 1376
        gemm_dq<<<dim3(nwg), dim3(512), 0, stream>>>(xb, qweight, scales, qzeros, out);
    } else {
        gptq_gemm_fused<<<dim3(OUT_F / BNf, M / BMf), dim3(256), 0, stream>>>(
            x, qweight, scales, qzeros, out);
    }
}

// Round 13
// 1040.289 us; speedup vs baseline: 1.0787x; 1.0787x over previous
//
#include <hip/hip_runtime.h>
#include <hip/hip_bf16.h>

#define IN_F 4096
#define OUT_F 11008

typedef __bf16 bf16_t;
typedef bf16_t bf16x8 __attribute__((ext_vector_type(8)));
typedef float f32x4 __attribute__((ext_vector_type(4)));
typedef unsigned int u32;

// ============================ pass 1a: x f32 -> bf16 ============================
__global__ __launch_bounds__(256) void cvt_x_kernel(const float* __restrict__ x,
                                                    bf16_t* __restrict__ xb) {
    size_t i = ((size_t)blockIdx.x * 256 + threadIdx.x) * 8;
    f32x4 v0 = __builtin_nontemporal_load((const f32x4*)(x + i));
    f32x4 v1 = __builtin_nontemporal_load((const f32x4*)(x + i + 4));
    bf16x8 h;
    h[0]=(bf16_t)v0[0]; h[1]=(bf16_t)v0[1]; h[2]=(bf16_t)v0[2]; h[3]=(bf16_t)v0[3];
    h[4]=(bf16_t)v1[0]; h[5]=(bf16_t)v1[1]; h[6]=(bf16_t)v1[2]; h[7]=(bf16_t)v1[3];
    *(bf16x8*)(xb + i) = h;
}

// ============ pass 2: 256x256 8-phase GEMM with in-register B dequant ============
// R12 = R11 concept with the two failure modes fixed:
//  - single w[8] buffer (was w0+w1: -8 VGPR, no spill). Ring: w=T0 at ph1,
//    overwritten ph2 (T1, after ph1's deq), ph6 (T2, after ph5's deq).
//  - EXACT vmcnt accounting including the w/scale register-load streams:
//    inter-phase VMEM issue order pinned by sched_barrier(0) at phase ends.
//    Flights/iter: ph1 stage(2), ph2 w(8)+sc(8 if nl), ph4 stage(2),
//    ph5 stage(2), ph6 w(8), ph8 stage(2).
//    ph4: confirm T1's A11(ph1):  younger = 16+2 -> vmcnt(18)  [!nl: 8]
//    ph8: confirm T2 (ph4+ph5):   younger = 8+2  -> vmcnt(10)
//    Each manual wait only drains loads >=3 phases old - no forced drains.

#define NI (IN_F / 128)   // 32 iterations = 32 groups, 64 K-tiles

__global__ __launch_bounds__(512, 2) void gemm_dq(const bf16_t* __restrict__ A,
                                                  const int* __restrict__ qweight,
                                                  const float* __restrict__ scales,
                                                  const int* __restrict__ qzeros,
                                                  float* __restrict__ C) {
    __shared__ __align__(16) bf16_t smemA[2 * 2 * 128 * 64];   // 64 KiB (A only)

    const int tid  = threadIdx.x;
    const int lane = tid & 63;
    const int wid  = tid >> 6;      // 0..7
    const int wr   = wid >> 2;      // 0..1  (M half)
    const int wc   = wid & 3;       // 0..3  (N quarter)

    // bijective XCD swizzle: nwg = 1376 = 8*172
    const int bid = blockIdx.x;
    const int swz = (bid & 7) * 172 + (bid >> 3);
    const int bx = swz % 43;
    const int by = swz / 43;
    const int m0 = by * 256;
    const int n0 = bx * 256;

    // A staging map: linear LDS slot -> inverse-swizzled global position
    int lr0, kb0, lr1, kb1;
    {
        int L0 = tid * 16;
        int p0 = L0 ^ (((L0 >> 7) & 7) << 4);
        lr0 = p0 >> 7; kb0 = (p0 & 127) >> 1;
        int L1 = (512 + tid) * 16;
        int p1 = L1 ^ (((L1 >> 7) & 7) << 4);
        lr1 = p1 >> 7; kb1 = (p1 & 127) >> 1;
    }

    // A fragment-read swizzled column byte offsets within a 128B row
    const int xm = (lane & 7) << 4;
    const int arow = lane & 15;
    int colk[2];
    #pragma unroll
    for (int ks = 0; ks < 2; ++ks)
        colk[ks] = ((ks * 64) + ((lane >> 4) * 16)) ^ xm;

    // B-side per-lane pointers (col = n0 + wc*64 + nt*16 + (lane&15))
    const int ncol = n0 + wc * 64 + (lane & 15);
    const int* qwp = qweight + (size_t)(lane >> 4) * OUT_F + ncol;
    const float* sp = scales + ncol;                 // + g*OUT_F + nt*16
    const int*   zp = qzeros + (ncol >> 3);          // + g*(OUT_F/8) + nt*2
    const int    zsh = (lane & 7) * 4;

#define STAGE_A(buf, half, koff)                                                           \
    do {                                                                                   \
        const bf16_t* g0_ = A + (size_t)(m0 + (half) * 128 + lr0) * IN_F + (koff) + kb0;   \
        __builtin_amdgcn_global_load_lds(                                                  \
            (const __attribute__((address_space(1))) u32*)g0_,                             \
            (__attribute__((address_space(3))) u32*)((char*)smemA + (buf) * 32768 +        \
                                                     (half) * 16384 + wid * 1024),         \
            16, 0, 0);                                                                     \
        const bf16_t* g1_ = A + (size_t)(m0 + (half) * 128 + lr1) * IN_F + (koff) + kb1;   \
        __builtin_amdgcn_global_load_lds(                                                  \
            (const __attribute__((address_space(1))) u32*)g1_,                             \
            (__attribute__((address_space(3))) u32*)((char*)smemA + (buf) * 32768 +        \
                                                     (half) * 16384 + 8192 + wid * 1024),  \
            16, 0, 0);                                                                     \
    } while (0)

// 8 ds_read_b128 -> aR : A fragments (4 m-tiles x 2 k-slices)
#define RD_A(dst, buf, mbase)                                                              \
    _Pragma("unroll") for (int mm = 0; mm < 4; ++mm)                                       \
    _Pragma("unroll") for (int ks = 0; ks < 2; ++ks)                                       \
        dst[mm * 2 + ks] = *(const bf16x8*)((const char*)smemA + (buf) * 32768 +           \
            wr * 16384 + (((mbase) + mm) * 16 + arow) * 128 + colk[ks]);

// 8 global u32: w[nt*2+ks] = qweight[base + rowoff + ks*4 + (lane>>4)][ncol + nt*16]
#define LOAD_W(dst, rowoff)                                                                \
    _Pragma("unroll") for (int nt = 0; nt < 4; ++nt)                                       \
    _Pragma("unroll") for (int ks = 0; ks < 2; ++ks)                                       \
        dst[nt * 2 + ks] = qwp[(size_t)((rowoff) + ks * 4) * OUT_F + nt * 16];

// dequant one B pair (n-tiles nt0, nt0+1; 2 k-slices) from w words
#define DEQ(dst, wArr, nt0)                                                                \
    _Pragma("unroll") for (int nn = 0; nn < 2; ++nn)                                       \
    _Pragma("unroll") for (int ks = 0; ks < 2; ++ks) {                                     \
        const int wv_ = wArr[((nt0) + nn) * 2 + ks];                                       \
        const float s_ = s0[(nt0) + nn];                                                   \
        const float z_ = nsz0[(nt0) + nn];                                                 \
        bf16x8 h_;                                                                         \
        _Pragma("unroll") for (int j = 0; j < 8; ++j)                                      \
            h_[j] = (bf16_t)fmaf((float)((wv_ >> (4 * j)) & 0xF), s_, z_);                 \
        dst[nn * 2 + ks] = h_;                                                             \
    }

// 16 MFMA: one quadrant (4 m x 2 n x 2 ks)
#define MFMA_Q(aArr, bArr, mbase, nbase)                                                   \
    __builtin_amdgcn_s_setprio(1);                                                         \
    _Pragma("unroll") for (int mm = 0; mm < 4; ++mm)                                       \
    _Pragma("unroll") for (int nn = 0; nn < 2; ++nn)                                       \
    _Pragma("unroll") for (int ks = 0; ks < 2; ++ks)                                       \
        acc[(mbase) + mm][(nbase) + nn] = __builtin_amdgcn_mfma_f32_16x16x32_bf16(         \
            aArr[mm * 2 + ks], bArr[nn * 2 + ks], acc[(mbase) + mm][(nbase) + nn],         \
            0, 0, 0);                                                                      \
    __builtin_amdgcn_s_setprio(0);

#define SCHED0() __builtin_amdgcn_sched_barrier(0)
#define BAR() do { SCHED0(); __builtin_amdgcn_s_barrier(); } while (0)
#define VMCNT18() asm volatile("s_waitcnt vmcnt(18)" ::: "memory")
#define VMCNT10() asm volatile("s_waitcnt vmcnt(10)" ::: "memory")
#define VMCNT8()  asm volatile("s_waitcnt vmcnt(8)"  ::: "memory")
#define VMCNT2()  asm volatile("s_waitcnt vmcnt(2)"  ::: "memory")

    f32x4 acc[8][4];
    #pragma unroll
    for (int m = 0; m < 8; ++m)
        #pragma unroll
        for (int n = 0; n < 4; ++n)
            acc[m][n] = (f32x4)0.0f;

    bf16x8 aR[8], b01[4], b23[4];
    int   w[8];
    float s0[4], nsz0[4];
    float sraw[4]; int zraw[4];

    // ---- prologue: w(T0) + group-0 scales first (their auto-waits are one-time),
    //      then stages; VMCNT(2) confirms T0's 4 stage loads (younger = A10's 2).
    LOAD_W(w, 0);
    #pragma unroll
    for (int nt = 0; nt < 4; ++nt) { sraw[nt] = sp[nt * 16]; zraw[nt] = zp[nt * 2]; }
    #pragma unroll
    for (int nt = 0; nt < 4; ++nt) {
        s0[nt] = sraw[nt];
        nsz0[nt] = -sraw[nt] * (float)(((zraw[nt] >> zsh) & 0xF) + 1);
    }
    DEQ(b01, w, 0);
    STAGE_A(0, 0, 0); STAGE_A(0, 1, 0);
    STAGE_A(1, 0, 64);
    VMCNT2();
    BAR();

    for (int i = 0; i < NI; ++i) {
        const int  kc = i * 128;        // T0 in buf0; T1 = kc+64 in buf1
        const int  kn = kc + 128;       // T2 in buf0; T3 = kn+64 in buf1
        const bool nl = (i + 1 < NI);

        // ph1: reads A(M0,buf0); stage A(1,1)(T1); deq b23(w=T0); MFMA(M0,N01)
        RD_A(aR, 0, 0);
        STAGE_A(1, 1, kc + 64);
        DEQ(b23, w, 2);
        MFMA_Q(aR, b01, 0, 0);
        BAR();
        // ph2: w <- T1 rows; scale raws for group i+1; MFMA(M0,N23)
        LOAD_W(w, 8);
        if (nl) {
            #pragma unroll
            for (int nt = 0; nt < 4; ++nt) {
                sraw[nt] = sp[(size_t)(i + 1) * OUT_F + nt * 16];
                zraw[nt] = zp[(size_t)(i + 1) * (OUT_F / 8) + nt * 2];
            }
        }
        MFMA_Q(aR, b23, 0, 2);
        BAR();
        // ph3: reads A(M1,buf0); MFMA(M1,N01)
        RD_A(aR, 0, 4);
        MFMA_Q(aR, b01, 4, 0);
        BAR();
        // ph4: stage A(0,0)(T2); deq b01(w=T1); MFMA(M1,N23); confirm T1's A
        if (nl) STAGE_A(0, 0, kn);
        DEQ(b01, w, 0);
        MFMA_Q(aR, b23, 4, 2);
        if (nl) VMCNT18(); else VMCNT8();
        BAR();
        // ph5: reads A(M0,buf1); stage A(0,1)(T2); deq b23(w=T1); MFMA(M0,N01)
        RD_A(aR, 1, 0);
        if (nl) STAGE_A(0, 1, kn);
        DEQ(b23, w, 2);
        MFMA_Q(aR, b01, 0, 0);
        BAR();
        // ph6: w <- T2 rows; MFMA(M0,N23)
        if (nl) LOAD_W(w, 16);
        MFMA_Q(aR, b23, 0, 2);
        BAR();
        // ph7: reads A(M1,buf1); convert group-(i+1) scales; MFMA(M1,N01)
        RD_A(aR, 1, 4);
        if (nl) {
            #pragma unroll
            for (int nt = 0; nt < 4; ++nt) {
                s0[nt] = sraw[nt];
                nsz0[nt] = -sraw[nt] * (float)(((zraw[nt] >> zsh) & 0xF) + 1);
            }
        }
        MFMA_Q(aR, b01, 4, 0);
        BAR();
        // ph8: stage A(1,0)(T3); deq b01(w=T2, group i+1); MFMA(M1,N23); confirm T2
        if (nl) {
            STAGE_A(1, 0, kn + 64);
            DEQ(b01, w, 0);
        }
        MFMA_Q(aR, b23, 4, 2);
        if (nl) VMCNT10();
        BAR();

        qwp += (size_t)16 * OUT_F;   // next 128-k block of qweight
    }

    // epilogue: C/D layout col = lane&15, row = (lane>>4)*4 + r
    const int cn  = lane & 15;
    const int cr4 = (lane >> 4) * 4;
    #pragma unroll
    for (int m = 0; m < 8; ++m) {
        #pragma unroll
        for (int r = 0; r < 4; ++r) {
            const int grow = m0 + wr * 128 + m * 16 + cr4 + r;
            float* orow = C + (size_t)grow * OUT_F + n0 + wc * 64 + cn;
            #pragma unroll
            for (int n = 0; n < 4; ++n)
                orow[n * 16] = acc[m][n][r];
        }
    }
}

// ===================== fallback: fused kernel (R0 structure) =====================
#define BMf 128
#define BNf 128
#define BKf 32
#define LDPF 40

__global__ __launch_bounds__(256, 2) void gptq_gemm_fused(
    const float* __restrict__ x, const int* __restrict__ qweight,
    const float* __restrict__ scales, const int* __restrict__ qzeros,
    float* __restrict__ out)
{
    __shared__ bf16_t As[BMf * LDPF];
    __shared__ bf16_t Bs[BNf * LDPF];
    const int tid = threadIdx.x, lane = tid & 63, wid = tid >> 6;
    const int wr = wid >> 1, wc = wid & 1;
    const int m0 = blockIdx.y * BMf, n0 = blockIdx.x * BNf;
    const int a_row = tid >> 2, a_slot = tid & 3;
    const int b_k8l = tid >> 7, b_n = tid & 127;

    f32x4 acc[4][4];
    #pragma unroll
    for (int i = 0; i < 4; ++i)
        #pragma unroll
        for (int j = 0; j < 4; ++j) acc[i][j] = (f32x4)0.0f;

    for (int kt = 0; kt < IN_F / BKf; ++kt) {
        const int k0 = kt * BKf;
        const int g  = k0 >> 7;
        __syncthreads();
        #pragma unroll
        for (int p = 0; p < 2; ++p) {
            const int row = a_row + p * 64;
            const float* src = x + (size_t)(m0 + row) * IN_F + k0 + a_slot * 8;
            f32x4 v0 = *(const f32x4*)src;
            f32x4 v1 = *(const f32x4*)(src + 4);
            bf16x8 h;
            h[0]=(bf16_t)v0[0]; h[1]=(bf16_t)v0[1]; h[2]=(bf16_t)v0[2]; h[3]=(bf16_t)v0[3];
            h[4]=(bf16_t)v1[0]; h[5]=(bf16_t)v1[1]; h[6]=(bf16_t)v1[2]; h[7]=(bf16_t)v1[3];
            *(bf16x8*)(&As[row * LDPF + a_slot * 8]) = h;
        }
        {
            const int gn = n0 + b_n;
            const float s  = scales[(size_t)g * OUT_F + gn];
            const int   zw = qzeros[(size_t)g * (OUT_F / 8) + (gn >> 3)];
            const float sz = s * (float)(((zw >> ((gn & 7) * 4)) & 0xF) + 1);
            #pragma unroll
            for (int p = 0; p < 2; ++p) {
                const int k8l = b_k8l + p * 2;
                const int w = qweight[(size_t)(k0 / 8 + k8l) * OUT_F + gn];
                bf16x8 h;
                #pragma unroll
                for (int j = 0; j < 8; ++j)
                    h[j] = (bf16_t)fmaf((float)((w >> (4 * j)) & 0xF), s, -sz);
                *(bf16x8*)(&Bs[b_n * LDPF + k8l * 8]) = h;
            }
        }
        __syncthreads();
        bf16x8 af[4], bfr[4];
        #pragma unroll
        for (int m = 0; m < 4; ++m)
            af[m] = *(const bf16x8*)(&As[(wr * 64 + m * 16 + (lane & 15)) * LDPF + (lane >> 4) * 8]);
        #pragma unroll
        for (int n = 0; n < 4; ++n)
            bfr[n] = *(const bf16x8*)(&Bs[(wc * 64 + n * 16 + (lane & 15)) * LDPF + (lane >> 4) * 8]);
        #pragma unroll
        for (int m = 0; m < 4; ++m)
            #pragma unroll
            for (int n = 0; n < 4; ++n)
                acc[m][n] = __builtin_amdgcn_mfma_f32_16x16x32_bf16(af[m], bfr[n], acc[m][n], 0, 0, 0);
    }
    const int cn = lane & 15, cr4 = (lane >> 4) * 4;
    #pragma unroll
    for (int m = 0; m < 4; ++m)
        #pragma unroll
        for (int r = 0; r < 4; ++r) {
            const int grow = m0 + wr * 64 + m * 16 + cr4 + r;
            float* orow = out + (size_t)grow * OUT_F + n0 + wc * 64 + cn;
            #pragma unroll
            for (int n = 0; n < 4; ++n) orow[n * 16] = acc[m][n][r];
        }
}

extern "C" void kernel_launch(void* const* d_in, const int* in_sizes, int n_in,
                              void* d_out, int out_size, void* d_ws, size_t ws_size,
                              hipStream_t stream) {
    const float* x       = (const float*)d_in[0];
    const int*   qweight = (const int*)d_in[1];
    const float* scales  = (const float*)d_in[2];
    const int*   qzeros  = (const int*)d_in[3];
    float* out = (float*)d_out;

    const int M = in_sizes[0] / IN_F;                       // 8192
    const size_t xb_bytes = (size_t)M * IN_F * 2;           // 67 MB

    if (ws_size >= xb_bytes && (M % 256) == 0) {
        bf16_t* xb = (bf16_t*)d_ws;
        cvt_x_kernel<<<dim3((M * IN_F) / (256 * 8)), dim3(256), 0, stream>>>(x, xb);
        const int nwg = (OUT_F / 256) * (M / 256);          // 43*32 = 1376
        gemm_dq<<<dim3(nwg), dim3(512), 0, stream>>>(xb, qweight, scales, qzeros, out);
    } else {
        gptq_gemm_fused<<<dim3(OUT_F / BNf, M / BMf), dim3(256), 0, stream>>>(
            x, qweight, scales, qzeros, out);
    }
}

// Round 14
// 1001.282 us; speedup vs baseline: 1.1207x; 1.0390x over previous
//
#include <hip/hip_runtime.h>
#include <hip/hip_bf16.h>

#define IN_F 4096
#define OUT_F 11008

typedef __bf16 bf16_t;
typedef bf16_t bf16x8 __attribute__((ext_vector_type(8)));
typedef float f32x4 __attribute__((ext_vector_type(4)));
typedef unsigned int u32;

// ============================ pass 1a: x f32 -> bf16 ============================
__global__ __launch_bounds__(256) void cvt_x_kernel(const float* __restrict__ x,
                                                    bf16_t* __restrict__ xb) {
    size_t i = ((size_t)blockIdx.x * 256 + threadIdx.x) * 8;
    f32x4 v0 = __builtin_nontemporal_load((const f32x4*)(x + i));
    f32x4 v1 = __builtin_nontemporal_load((const f32x4*)(x + i + 4));
    bf16x8 h;
    h[0]=(bf16_t)v0[0]; h[1]=(bf16_t)v0[1]; h[2]=(bf16_t)v0[2]; h[3]=(bf16_t)v0[3];
    h[4]=(bf16_t)v1[0]; h[5]=(bf16_t)v1[1]; h[6]=(bf16_t)v1[2]; h[7]=(bf16_t)v1[3];
    *(bf16x8*)(xb + i) = h;
}

// ============ pass 2: 256x256 8-phase GEMM with in-register B dequant ============
// R13 = R8 A-side skeleton verbatim + in-reg B with the R12 failure modes fixed:
//  (a) 32-bit-index addressing for qweight/scales/qzeros: s_base[v_idx32+imm]
//      form - no 64-bit per-lane address materialization (R12's 16-reg spike).
//  (b) ubyte dequant: spread nibbles to bytes once (2 ops), then
//      v_cvt_f32_ubyte0..3 - ~25% fewer VALU ops than bfe+cvt_u32.
//  (c) exact oldest-first vmcnt: per-iter pinned stream
//      {ph1 st2, ph3 w8, ph4 st2, ph5 st2, ph6 sc8, ph7 w8, ph8 st2};
//      ph4 vmcnt(10) [!nl: 8] confirms A11(T1); ph8 vmcnt(10) confirms T2
//      (leaves exactly ph7 w8 + ph8 st2 in flight - drains only >=2-phase-old).

#define NI (IN_F / 128)   // 32 iterations = 32 groups, 64 K-tiles

__global__ __launch_bounds__(512, 2) void gemm_dq(const bf16_t* __restrict__ A,
                                                  const int* __restrict__ qweight,
                                                  const float* __restrict__ scales,
                                                  const int* __restrict__ qzeros,
                                                  float* __restrict__ C) {
    __shared__ __align__(16) bf16_t smemA[2 * 2 * 128 * 64];   // 64 KiB (A only)

    const int tid  = threadIdx.x;
    const int lane = tid & 63;
    const int wid  = tid >> 6;      // 0..7
    const int wr   = wid >> 2;      // 0..1  (M half)
    const int wc   = wid & 3;       // 0..3  (N quarter)

    // bijective XCD swizzle: nwg = 1376 = 8*172
    const int bid = blockIdx.x;
    const int swz = (bid & 7) * 172 + (bid >> 3);
    const int bx = swz % 43;
    const int by = swz / 43;
    const int m0 = by * 256;
    const int n0 = bx * 256;

    // A staging map: linear LDS slot -> inverse-swizzled global position
    int lr0, kb0, lr1, kb1;
    {
        int L0 = tid * 16;
        int p0 = L0 ^ (((L0 >> 7) & 7) << 4);
        lr0 = p0 >> 7; kb0 = (p0 & 127) >> 1;
        int L1 = (512 + tid) * 16;
        int p1 = L1 ^ (((L1 >> 7) & 7) << 4);
        lr1 = p1 >> 7; kb1 = (p1 & 127) >> 1;
    }

    // A fragment-read swizzled column byte offsets within a 128B row
    const int xm = (lane & 7) << 4;
    const int arow = lane & 15;
    int colk[2];
    #pragma unroll
    for (int ks = 0; ks < 2; ++ks)
        colk[ks] = ((ks * 64) + ((lane >> 4) * 16)) ^ xm;

    // B-side 32-bit per-lane indices (s_base + v_idx addressing; no 64-bit VGPR addrs)
    const int ncol = n0 + wc * 64 + (lane & 15);
    const int qidx = (lane >> 4) * OUT_F + ncol;   // + uniform row*OUT_F + nt*16
    const int zidx = ncol >> 3;                    // + uniform g*(OUT_F/8) + nt*2
    const int zsh  = (lane & 7) * 4;

#define STAGE_A(buf, half, koff)                                                           \
    do {                                                                                   \
        const bf16_t* g0_ = A + (size_t)(m0 + (half) * 128 + lr0) * IN_F + (koff) + kb0;   \
        __builtin_amdgcn_global_load_lds(                                                  \
            (const __attribute__((address_space(1))) u32*)g0_,                             \
            (__attribute__((address_space(3))) u32*)((char*)smemA + (buf) * 32768 +        \
                                                     (half) * 16384 + wid * 1024),         \
            16, 0, 0);                                                                     \
        const bf16_t* g1_ = A + (size_t)(m0 + (half) * 128 + lr1) * IN_F + (koff) + kb1;   \
        __builtin_amdgcn_global_load_lds(                                                  \
            (const __attribute__((address_space(1))) u32*)g1_,                             \
            (__attribute__((address_space(3))) u32*)((char*)smemA + (buf) * 32768 +        \
                                                     (half) * 16384 + 8192 + wid * 1024),  \
            16, 0, 0);                                                                     \
    } while (0)

// 8 ds_read_b128 -> aR : A fragments (4 m-tiles x 2 k-slices)
#define RD_A(dst, buf, mbase)                                                              \
    _Pragma("unroll") for (int mm = 0; mm < 4; ++mm)                                       \
    _Pragma("unroll") for (int ks = 0; ks < 2; ++ks)                                       \
        dst[mm * 2 + ks] = *(const bf16x8*)((const char*)smemA + (buf) * 32768 +           \
            wr * 16384 + (((mbase) + mm) * 16 + arow) * 128 + colk[ks]);

// 8 global u32 via 32-bit index: rowAbs = uniform absolute qweight row base
#define LOAD_W(rowAbs)                                                                     \
    _Pragma("unroll") for (int nt = 0; nt < 4; ++nt)                                       \
    _Pragma("unroll") for (int ks = 0; ks < 2; ++ks)                                       \
        w[nt * 2 + ks] = ((const u32*)qweight)[qidx + ((rowAbs) + ks * 4) * OUT_F + nt * 16];

// dequant one B pair (n-tiles nt0..nt0+1, 2 ks) via ubyte spread
#define DEQ(dst, nt0)                                                                      \
    _Pragma("unroll") for (int nn = 0; nn < 2; ++nn)                                       \
    _Pragma("unroll") for (int ks = 0; ks < 2; ++ks) {                                     \
        const u32 wv_ = w[((nt0) + nn) * 2 + ks];                                          \
        const u32 ev_ = wv_ & 0x0F0F0F0Fu;                                                 \
        const u32 od_ = (wv_ >> 4) & 0x0F0F0F0Fu;                                          \
        const float s_ = s0[(nt0) + nn];                                                   \
        const float z_ = nsz0[(nt0) + nn];                                                 \
        bf16x8 h_;                                                                         \
        h_[0] = (bf16_t)fmaf((float)(ev_ & 0xFF), s_, z_);                                 \
        h_[1] = (bf16_t)fmaf((float)(od_ & 0xFF), s_, z_);                                 \
        h_[2] = (bf16_t)fmaf((float)((ev_ >> 8) & 0xFF), s_, z_);                          \
        h_[3] = (bf16_t)fmaf((float)((od_ >> 8) & 0xFF), s_, z_);                          \
        h_[4] = (bf16_t)fmaf((float)((ev_ >> 16) & 0xFF), s_, z_);                         \
        h_[5] = (bf16_t)fmaf((float)((od_ >> 16) & 0xFF), s_, z_);                         \
        h_[6] = (bf16_t)fmaf((float)(ev_ >> 24), s_, z_);                                  \
        h_[7] = (bf16_t)fmaf((float)(od_ >> 24), s_, z_);                                  \
        dst[nn * 2 + ks] = h_;                                                             \
    }

// 16 MFMA: one quadrant (4 m x 2 n x 2 ks)
#define MFMA_Q(aArr, bArr, mbase, nbase)                                                   \
    __builtin_amdgcn_s_setprio(1);                                                         \
    _Pragma("unroll") for (int mm = 0; mm < 4; ++mm)                                       \
    _Pragma("unroll") for (int nn = 0; nn < 2; ++nn)                                       \
    _Pragma("unroll") for (int ks = 0; ks < 2; ++ks)                                       \
        acc[(mbase) + mm][(nbase) + nn] = __builtin_amdgcn_mfma_f32_16x16x32_bf16(         \
            aArr[mm * 2 + ks], bArr[nn * 2 + ks], acc[(mbase) + mm][(nbase) + nn],         \
            0, 0, 0);                                                                      \
    __builtin_amdgcn_s_setprio(0);

#define SCHED0() __builtin_amdgcn_sched_barrier(0)
#define BAR() do { SCHED0(); __builtin_amdgcn_s_barrier(); } while (0)
#define VMCNT10() asm volatile("s_waitcnt vmcnt(10)" ::: "memory")
#define VMCNT8()  asm volatile("s_waitcnt vmcnt(8)"  ::: "memory")

    f32x4 acc[8][4];
    #pragma unroll
    for (int m = 0; m < 8; ++m)
        #pragma unroll
        for (int n = 0; n < 4; ++n)
            acc[m][n] = (f32x4)0.0f;

    bf16x8 aR[8], b01[4], b23[4];
    u32   w[8];
    float s0[4], nsz0[4];
    float sraw[4]; u32 zraw[4];

    // ---- prologue: stage T0 + A10(T1); w <- T0 rows; group-0 scales; convert.
    // The convert's auto-wait drains everything (one-time) -> enter loop clean.
    STAGE_A(0, 0, 0); STAGE_A(0, 1, 0);
    STAGE_A(1, 0, 64);
    LOAD_W(0);
    #pragma unroll
    for (int nt = 0; nt < 4; ++nt) {
        sraw[nt] = scales[ncol + nt * 16];
        zraw[nt] = ((const u32*)qzeros)[zidx + nt * 2];
    }
    #pragma unroll
    for (int nt = 0; nt < 4; ++nt) {
        s0[nt] = sraw[nt];
        nsz0[nt] = -sraw[nt] * (float)(((zraw[nt] >> zsh) & 0xF) + 1);
    }
    BAR();

    for (int i = 0; i < NI; ++i) {
        const int  kc = i * 128;        // T0 in buf0; T1 = kc+64 in buf1
        const int  kn = kc + 128;       // T2 in buf0; T3 = kn+64 in buf1
        const int  rw = i * 16;         // qweight row base for T0
        const bool nl = (i + 1 < NI);

        // ph1: reads A(M0,buf0); stage A(1,1)(T1); deq b01(w=T0); MFMA(M0,N01)
        RD_A(aR, 0, 0);
        STAGE_A(1, 1, kc + 64);
        DEQ(b01, 0);
        MFMA_Q(aR, b01, 0, 0);
        BAR();
        // ph2: deq b23(w=T0); MFMA(M0,N23)
        DEQ(b23, 2);
        MFMA_Q(aR, b23, 0, 2);
        BAR();
        // ph3: reads A(M1,buf0); w <- T1 rows; MFMA(M1,N01)
        RD_A(aR, 0, 4);
        LOAD_W(rw + 8);
        MFMA_Q(aR, b01, 4, 0);
        BAR();
        // ph4: stage A(0,0)(T2); MFMA(M1,N23); confirm A11(T1)
        if (nl) STAGE_A(0, 0, kn);
        MFMA_Q(aR, b23, 4, 2);
        if (nl) VMCNT10(); else VMCNT8();
        BAR();
        // ph5: reads A(M0,buf1); stage A(0,1)(T2); deq b01(w=T1); MFMA(M0,N01)
        RD_A(aR, 1, 0);
        if (nl) STAGE_A(0, 1, kn);
        DEQ(b01, 0);
        MFMA_Q(aR, b01, 0, 0);
        BAR();
        // ph6: scale raws for group i+1; deq b23(w=T1); MFMA(M0,N23)
        if (nl) {
            #pragma unroll
            for (int nt = 0; nt < 4; ++nt) {
                sraw[nt] = scales[ncol + (i + 1) * OUT_F + nt * 16];
                zraw[nt] = ((const u32*)qzeros)[zidx + (i + 1) * (OUT_F / 8) + nt * 2];
            }
        }
        DEQ(b23, 2);
        MFMA_Q(aR, b23, 0, 2);
        BAR();
        // ph7: reads A(M1,buf1); w <- T2 rows; convert group-(i+1) scales; MFMA(M1,N01)
        RD_A(aR, 1, 4);
        if (nl) {
            LOAD_W(rw + 16);
            #pragma unroll
            for (int nt = 0; nt < 4; ++nt) {
                s0[nt] = sraw[nt];
                nsz0[nt] = -sraw[nt] * (float)(((zraw[nt] >> zsh) & 0xF) + 1);
            }
        }
        MFMA_Q(aR, b01, 4, 0);
        BAR();
        // ph8: stage A(1,0)(T3); MFMA(M1,N23); confirm T2 (leaves ph7 w + ph8 st in flight)
        if (nl) STAGE_A(1, 0, kn + 64);
        MFMA_Q(aR, b23, 4, 2);
        if (nl) VMCNT10();
        BAR();
    }

    // epilogue: C/D layout col = lane&15, row = (lane>>4)*4 + r
    const int cn  = lane & 15;
    const int cr4 = (lane >> 4) * 4;
    #pragma unroll
    for (int m = 0; m < 8; ++m) {
        #pragma unroll
        for (int r = 0; r < 4; ++r) {
            const int grow = m0 + wr * 128 + m * 16 + cr4 + r;
            float* orow = C + (size_t)grow * OUT_F + n0 + wc * 64 + cn;
            #pragma unroll
            for (int n = 0; n < 4; ++n)
                orow[n * 16] = acc[m][n][r];
        }
    }
}

// ===================== fallback: fused kernel (R0 structure) =====================
#define BMf 128
#define BNf 128
#define BKf 32
#define LDPF 40

__global__ __launch_bounds__(256, 2) void gptq_gemm_fused(
    const float* __restrict__ x, const int* __restrict__ qweight,
    const float* __restrict__ scales, const int* __restrict__ qzeros,
    float* __restrict__ out)
{
    __shared__ bf16_t As[BMf * LDPF];
    __shared__ bf16_t Bs[BNf * LDPF];
    const int tid = threadIdx.x, lane = tid & 63, wid = tid >> 6;
    const int wr = wid >> 1, wc = wid & 1;
    const int m0 = blockIdx.y * BMf, n0 = blockIdx.x * BNf;
    const int a_row = tid >> 2, a_slot = tid & 3;
    const int b_k8l = tid >> 7, b_n = tid & 127;

    f32x4 acc[4][4];
    #pragma unroll
    for (int i = 0; i < 4; ++i)
        #pragma unroll
        for (int j = 0; j < 4; ++j) acc[i][j] = (f32x4)0.0f;

    for (int kt = 0; kt < IN_F / BKf; ++kt) {
        const int k0 = kt * BKf;
        const int g  = k0 >> 7;
        __syncthreads();
        #pragma unroll
        for (int p = 0; p < 2; ++p) {
            const int row = a_row + p * 64;
            const float* src = x + (size_t)(m0 + row) * IN_F + k0 + a_slot * 8;
            f32x4 v0 = *(const f32x4*)src;
            f32x4 v1 = *(const f32x4*)(src + 4);
            bf16x8 h;
            h[0]=(bf16_t)v0[0]; h[1]=(bf16_t)v0[1]; h[2]=(bf16_t)v0[2]; h[3]=(bf16_t)v0[3];
            h[4]=(bf16_t)v1[0]; h[5]=(bf16_t)v1[1]; h[6]=(bf16_t)v1[2]; h[7]=(bf16_t)v1[3];
            *(bf16x8*)(&As[row * LDPF + a_slot * 8]) = h;
        }
        {
            const int gn = n0 + b_n;
            const float s  = scales[(size_t)g * OUT_F + gn];
            const int   zw = qzeros[(size_t)g * (OUT_F / 8) + (gn >> 3)];
            const float sz = s * (float)(((zw >> ((gn & 7) * 4)) & 0xF) + 1);
            #pragma unroll
            for (int p = 0; p < 2; ++p) {
                const int k8l = b_k8l + p * 2;
                const int w = qweight[(size_t)(k0 / 8 + k8l) * OUT_F + gn];
                bf16x8 h;
                #pragma unroll
                for (int j = 0; j < 8; ++j)
                    h[j] = (bf16_t)fmaf((float)((w >> (4 * j)) & 0xF), s, -sz);
                *(bf16x8*)(&Bs[b_n * LDPF + k8l * 8]) = h;
            }
        }
        __syncthreads();
        bf16x8 af[4], bfr[4];
        #pragma unroll
        for (int m = 0; m < 4; ++m)
            af[m] = *(const bf16x8*)(&As[(wr * 64 + m * 16 + (lane & 15)) * LDPF + (lane >> 4) * 8]);
        #pragma unroll
        for (int n = 0; n < 4; ++n)
            bfr[n] = *(const bf16x8*)(&Bs[(wc * 64 + n * 16 + (lane & 15)) * LDPF + (lane >> 4) * 8]);
        #pragma unroll
        for (int m = 0; m < 4; ++m)
            #pragma unroll
            for (int n = 0; n < 4; ++n)
                acc[m][n] = __builtin_amdgcn_mfma_f32_16x16x32_bf16(af[m], bfr[n], acc[m][n], 0, 0, 0);
    }
    const int cn = lane & 15, cr4 = (lane >> 4) * 4;
    #pragma unroll
    for (int m = 0; m < 4; ++m)
        #pragma unroll
        for (int r = 0; r < 4; ++r) {
            const int grow = m0 + wr * 64 + m * 16 + cr4 + r;
            float* orow = out + (size_t)grow * OUT_F + n0 + wc * 64 + cn;
            #pragma unroll
            for (int n = 0; n < 4; ++n) orow[n * 16] = acc[m][n][r];
        }
}

extern "C" void kernel_launch(void* const* d_in, const int* in_sizes, int n_in,
                              void* d_out, int out_size, void* d_ws, size_t ws_size,
                              hipStream_t stream) {
    const float* x       = (const float*)d_in[0];
    const int*   qweight = (const int*)d_in[1];
    const float* scales  = (const float*)d_in[2];
    const int*   qzeros  = (const int*)d_in[3];
    float* out = (float*)d_out;

    const int M = in_sizes[0] / IN_F;                       // 8192
    const size_t xb_bytes = (size_t)M * IN_F * 2;           // 67 MB

    if (ws_size >= xb_bytes && (M % 256) == 0) {
        bf16_t* xb = (bf16_t*)d_ws;
        cvt_x_kernel<<<dim3((M * IN_F) / (256 * 8)), dim3(256), 0, stream>>>(x, xb);
        const int nwg = (OUT_F / 256) * (M / 256);          // 43*32 = 1376
        gemm_dq<<<dim3(nwg), dim3(512), 0, stream>>>(xb, qweight, scales, qzeros, out);
    } else {
        gptq_gemm_fused<<<dim3(OUT_F / BNf, M / BMf), dim3(256), 0, stream>>>(
            x, qweight, scales, qzeros, out);
    }
}

// Round 16
// 843.842 us; speedup vs baseline: 1.3298x; 1.1866x over previous
//
#include <hip/hip_runtime.h>
#include <hip/hip_bf16.h>

#define IN_F 4096
#define OUT_F 11008

typedef __bf16 bf16_t;
typedef bf16_t bf16x8 __attribute__((ext_vector_type(8)));
typedef float f32x4 __attribute__((ext_vector_type(4)));
typedef unsigned int u32;

// ============================ pass 1a: x f32 -> bf16 ============================
__global__ __launch_bounds__(256) void cvt_x_kernel(const float* __restrict__ x,
                                                    bf16_t* __restrict__ xb) {
    size_t i = ((size_t)blockIdx.x * 256 + threadIdx.x) * 8;
    f32x4 v0 = __builtin_nontemporal_load((const f32x4*)(x + i));
    f32x4 v1 = __builtin_nontemporal_load((const f32x4*)(x + i + 4));
    bf16x8 h;
    h[0]=(bf16_t)v0[0]; h[1]=(bf16_t)v0[1]; h[2]=(bf16_t)v0[2]; h[3]=(bf16_t)v0[3];
    h[4]=(bf16_t)v1[0]; h[5]=(bf16_t)v1[1]; h[6]=(bf16_t)v1[2]; h[7]=(bf16_t)v1[3];
    *(bf16x8*)(xb + i) = h;
}

// ========== pass 2: 256x256 8-phase GEMM, B staged as RAW 4-BIT in LDS ==========
// R15 = R14's design with the sync made ORDER-ROBUST (R14 raced):
//  - BAR() = sched_barrier(0) + s_barrier: loads confined to their phase.
//  - prologue barrier after RD_W/DEQ: ph1's STAGE_B can no longer overwrite
//    B-buf0 while another wave still reads T0 words (R14's race).
//  - vmcnt counts invariant to intra-phase issue order (smemA/smemB stages
//    may be reordered by AA within a phase):
//      prologue vmcnt(0) (one-time drain);
//      ph4 vmcnt(10): drains entering A10(2) + ALL of ph1 {A11x2,B0} ->
//                     T1-A confirmed; keeps sc(8)+A00(2).
//      ph8 vmcnt(2):  keeps only ph8's A10(2) -> T2 A00/A01/B0 all
//                     published (sc8 already consumed; B1 drained early, ok).
// B LDS: [2 buf][2048] u32; per K-tile u32 idx = 512*wc+128*nt+64*ks
//   +16*(lane>>4)+(lane&15); stage dest linear tid*16B; 2-way banks (free).

#define NI (IN_F / 128)   // 32 iterations = 32 groups, 64 K-tiles

__global__ __launch_bounds__(512, 2) void gemm_q4(const bf16_t* __restrict__ A,
                                                  const int* __restrict__ qweight,
                                                  const float* __restrict__ scales,
                                                  const int* __restrict__ qzeros,
                                                  float* __restrict__ C) {
    __shared__ __align__(16) bf16_t smemA[2 * 2 * 128 * 64];   // 64 KiB
    __shared__ __align__(16) u32    smemB[2 * 2048];           // 16 KiB (4-bit B)

    const int tid  = threadIdx.x;
    const int lane = tid & 63;
    const int wid  = tid >> 6;      // 0..7
    const int wr   = wid >> 2;      // 0..1  (M half)
    const int wc   = wid & 3;       // 0..3  (N quarter)

    // bijective XCD swizzle: nwg = 1376 = 8*172
    const int bid = blockIdx.x;
    const int swz = (bid & 7) * 172 + (bid >> 3);
    const int bx = swz % 43;
    const int by = swz / 43;
    const int m0 = by * 256;
    const int n0 = bx * 256;

    // A staging map: linear LDS slot -> inverse-swizzled global position
    int lr0, kb0, lr1, kb1;
    {
        int L0 = tid * 16;
        int p0 = L0 ^ (((L0 >> 7) & 7) << 4);
        lr0 = p0 >> 7; kb0 = (p0 & 127) >> 1;
        int L1 = (512 + tid) * 16;
        int p1 = L1 ^ (((L1 >> 7) & 7) << 4);
        lr1 = p1 >> 7; kb1 = (p1 & 127) >> 1;
    }

    // A fragment-read swizzled column byte offsets within a 128B row
    const int xm = (lane & 7) << 4;
    const int arow = lane & 15;
    int colk[2];
    #pragma unroll
    for (int ks = 0; ks < 2; ++ks)
        colk[ks] = ((ks * 64) + ((lane >> 4) * 16)) ^ xm;

    // B-side: per-lane LDS word base; per-thread stage source pointer
    const int ncol = n0 + wc * 64 + (lane & 15);
    const u32* bw = smemB + (wc * 512 + (lane >> 4) * 16 + (lane & 15));
    const int kwS  = (tid >> 2) & 7;
    const int colS = (tid >> 5) * 16 + (tid & 3) * 4;
    const u32* qB = (const u32*)qweight + (size_t)kwS * OUT_F + n0 + colS;
    const int zsh = (lane & 7) * 4;

#define STAGE_A(buf, half, koff)                                                           \
    do {                                                                                   \
        const bf16_t* g0_ = A + (size_t)(m0 + (half) * 128 + lr0) * IN_F + (koff) + kb0;   \
        __builtin_amdgcn_global_load_lds(                                                  \
            (const __attribute__((address_space(1))) u32*)g0_,                             \
            (__attribute__((address_space(3))) u32*)((char*)smemA + (buf) * 32768 +        \
                                                     (half) * 16384 + wid * 1024),         \
            16, 0, 0);                                                                     \
        const bf16_t* g1_ = A + (size_t)(m0 + (half) * 128 + lr1) * IN_F + (koff) + kb1;   \
        __builtin_amdgcn_global_load_lds(                                                  \
            (const __attribute__((address_space(1))) u32*)g1_,                             \
            (__attribute__((address_space(3))) u32*)((char*)smemA + (buf) * 32768 +        \
                                                     (half) * 16384 + 8192 + wid * 1024),  \
            16, 0, 0);                                                                     \
    } while (0)

// B stage: one width-16 load/thread; dest linear; src = qweight row (ktrow+kwS)
#define STAGE_B(buf, ktrow)                                                                \
    __builtin_amdgcn_global_load_lds(                                                      \
        (const __attribute__((address_space(1))) u32*)(qB + (size_t)(ktrow) * OUT_F),      \
        (__attribute__((address_space(3))) u32*)((char*)smemB + (buf) * 8192 + tid * 16),  \
        16, 0, 0)

// 8 ds_read_b128 -> aR : A fragments (4 m-tiles x 2 k-slices)
#define RD_A(dst, buf, mbase)                                                              \
    _Pragma("unroll") for (int mm = 0; mm < 4; ++mm)                                       \
    _Pragma("unroll") for (int ks = 0; ks < 2; ++ks)                                       \
        dst[mm * 2 + ks] = *(const bf16x8*)((const char*)smemA + (buf) * 32768 +           \
            wr * 16384 + (((mbase) + mm) * 16 + arow) * 128 + colk[ks]);

// 8 ds_read_b32 (base + compile-time imm): all 4 n-tiles x 2 ks of one buffer
#define RD_W(buf)                                                                          \
    _Pragma("unroll") for (int nt = 0; nt < 4; ++nt)                                       \
    _Pragma("unroll") for (int ks = 0; ks < 2; ++ks)                                       \
        w[nt * 2 + ks] = bw[(buf) * 2048 + nt * 128 + ks * 64];

// dequant one B pair (n-tiles nt0..nt0+1, 2 ks) via ubyte spread (R13-validated)
#define DEQ(dst, nt0)                                                                      \
    _Pragma("unroll") for (int nn = 0; nn < 2; ++nn)                                       \
    _Pragma("unroll") for (int ks = 0; ks < 2; ++ks) {                                     \
        const u32 wv_ = w[((nt0) + nn) * 2 + ks];                                          \
        const u32 ev_ = wv_ & 0x0F0F0F0Fu;                                                 \
        const u32 od_ = (wv_ >> 4) & 0x0F0F0F0Fu;                                          \
        const float s_ = s0[(nt0) + nn];                                                   \
        const float z_ = nsz0[(nt0) + nn];                                                 \
        bf16x8 h_;                                                                         \
        h_[0] = (bf16_t)fmaf((float)(ev_ & 0xFF), s_, z_);                                 \
        h_[1] = (bf16_t)fmaf((float)(od_ & 0xFF), s_, z_);                                 \
        h_[2] = (bf16_t)fmaf((float)((ev_ >> 8) & 0xFF), s_, z_);                          \
        h_[3] = (bf16_t)fmaf((float)((od_ >> 8) & 0xFF), s_, z_);                          \
        h_[4] = (bf16_t)fmaf((float)((ev_ >> 16) & 0xFF), s_, z_);                         \
        h_[5] = (bf16_t)fmaf((float)((od_ >> 16) & 0xFF), s_, z_);                         \
        h_[6] = (bf16_t)fmaf((float)(ev_ >> 24), s_, z_);                                  \
        h_[7] = (bf16_t)fmaf((float)(od_ >> 24), s_, z_);                                  \
        dst[nn * 2 + ks] = h_;                                                             \
    }

// 16 MFMA: one quadrant (4 m x 2 n x 2 ks)
#define MFMA_Q(aArr, bArr, mbase, nbase)                                                   \
    __builtin_amdgcn_s_setprio(1);                                                         \
    _Pragma("unroll") for (int mm = 0; mm < 4; ++mm)                                       \
    _Pragma("unroll") for (int nn = 0; nn < 2; ++nn)                                       \
    _Pragma("unroll") for (int ks = 0; ks < 2; ++ks)                                       \
        acc[(mbase) + mm][(nbase) + nn] = __builtin_amdgcn_mfma_f32_16x16x32_bf16(         \
            aArr[mm * 2 + ks], bArr[nn * 2 + ks], acc[(mbase) + mm][(nbase) + nn],         \
            0, 0, 0);                                                                      \
    __builtin_amdgcn_s_setprio(0);

#define SCHED0() __builtin_amdgcn_sched_barrier(0)
#define BAR() do { SCHED0(); __builtin_amdgcn_s_barrier(); } while (0)
#define VMCNT10() asm volatile("s_waitcnt vmcnt(10)" ::: "memory")
#define VMCNT2()  asm volatile("s_waitcnt vmcnt(2)"  ::: "memory")
#define VMCNT0()  asm volatile("s_waitcnt vmcnt(0)"  ::: "memory")

    f32x4 acc[8][4];
    #pragma unroll
    for (int m = 0; m < 8; ++m)
        #pragma unroll
        for (int n = 0; n < 4; ++n)
            acc[m][n] = (f32x4)0.0f;

    bf16x8 aR[8], b01[4], b23[4];
    u32   w[8];
    float s0[4], nsz0[4];
    float sraw[4]; u32 zraw[4];

    // ---- prologue: stage A-buf0(T0), B-buf0(T0), B-buf1(T1), A10(T1);
    //      drain ALL (one-time, order-robust); scales group 0; deq T0 pairs;
    //      barrier so no wave can enter ph1's STAGE_B while others read T0.
    STAGE_A(0, 0, 0); STAGE_A(0, 1, 0);
    STAGE_B(0, 0);
    STAGE_B(1, 8);
    STAGE_A(1, 0, 64);
    VMCNT0();
    BAR();
    #pragma unroll
    for (int nt = 0; nt < 4; ++nt) {
        sraw[nt] = scales[ncol + nt * 16];
        zraw[nt] = ((const u32*)qzeros)[(ncol >> 3) + nt * 2];
    }
    #pragma unroll
    for (int nt = 0; nt < 4; ++nt) {
        s0[nt] = sraw[nt];
        nsz0[nt] = -sraw[nt] * (float)(((zraw[nt] >> zsh) & 0xF) + 1);
    }
    RD_W(0);
    DEQ(b01, 0);
    DEQ(b23, 2);
    BAR();   // R15: kills the prologue->ph1 B-buf0 WAR race

    for (int i = 0; i < NI; ++i) {
        const int  kc = i * 128;        // T0 in buf0; T1 = kc+64 in buf1
        const int  kn = kc + 128;       // T2 in buf0; T3 = kn+64 in buf1
        const bool nl = (i + 1 < NI);

        // ph1: reads A(M0,buf0); stage A11(T1), B-buf0(T2); MFMA(M0,N01)
        RD_A(aR, 0, 0);
        STAGE_A(1, 1, kc + 64);
        if (nl) STAGE_B(0, (kn) >> 3);
        MFMA_Q(aR, b01, 0, 0);
        BAR();
        // ph2: scale raws for group i+1 (8 vmem, confined here); MFMA(M0,N23)
        if (nl) {
            #pragma unroll
            for (int nt = 0; nt < 4; ++nt) {
                sraw[nt] = scales[ncol + (i + 1) * OUT_F + nt * 16];
                zraw[nt] = ((const u32*)qzeros)[(ncol >> 3) + (i + 1) * (OUT_F / 8) + nt * 2];
            }
        }
        MFMA_Q(aR, b23, 0, 2);
        BAR();
        // ph3: reads A(M1,buf0); MFMA(M1,N01)
        RD_A(aR, 0, 4);
        MFMA_Q(aR, b01, 4, 0);
        BAR();
        // ph4: stage A00(T2); MFMA(M1,N23); vmcnt(10) -> T1-A complete
        //      (drains entering A10 + all of ph1; keeps sc8+A00); deq T1 pairs
        if (nl) STAGE_A(0, 0, kn);
        MFMA_Q(aR, b23, 4, 2);
        if (nl) VMCNT10(); else VMCNT0();
        RD_W(1);
        DEQ(b01, 0);
        DEQ(b23, 2);
        BAR();
        // ph5: reads A(M0,buf1); stage A01(T2), B-buf1(T3); MFMA(M0,N01)
        RD_A(aR, 1, 0);
        if (nl) { STAGE_A(0, 1, kn); STAGE_B(1, (kn + 64) >> 3); }
        MFMA_Q(aR, b01, 0, 0);
        BAR();
        // ph6: MFMA(M0,N23)
        MFMA_Q(aR, b23, 0, 2);
        BAR();
        // ph7: reads A(M1,buf1); convert group-(i+1) scales; MFMA(M1,N01)
        RD_A(aR, 1, 4);
        if (nl) {
            #pragma unroll
            for (int nt = 0; nt < 4; ++nt) {
                s0[nt] = sraw[nt];
                nsz0[nt] = -sraw[nt] * (float)(((zraw[nt] >> zsh) & 0xF) + 1);
            }
        }
        MFMA_Q(aR, b01, 4, 0);
        BAR();
        // ph8: stage A10(T3); MFMA(M1,N23); vmcnt(2) -> keeps only A10(T3):
        //      T2's A00/A01/B0 all published; w-reads of T2 after the wait;
        //      deq T2 pairs (group i+1 scales)
        if (nl) STAGE_A(1, 0, kn + 64);
        MFMA_Q(aR, b23, 4, 2);
        if (nl) VMCNT2(); else VMCNT0();
        if (nl) {
            RD_W(0);
            DEQ(b01, 0);
            DEQ(b23, 2);
        }
        BAR();
    }

    // epilogue: C/D layout col = lane&15, row = (lane>>4)*4 + r
    const int cn  = lane & 15;
    const int cr4 = (lane >> 4) * 4;
    #pragma unroll
    for (int m = 0; m < 8; ++m) {
        #pragma unroll
        for (int r = 0; r < 4; ++r) {
            const int grow = m0 + wr * 128 + m * 16 + cr4 + r;
            float* orow = C + (size_t)grow * OUT_F + n0 + wc * 64 + cn;
            #pragma unroll
            for (int n = 0; n < 4; ++n)
                orow[n * 16] = acc[m][n][r];
        }
    }
}

// ===================== fallback: fused kernel (R0 structure) =====================
#define BMf 128
#define BNf 128
#define BKf 32
#define LDPF 40

__global__ __launch_bounds__(256, 2) void gptq_gemm_fused(
    const float* __restrict__ x, const int* __restrict__ qweight,
    const float* __restrict__ scales, const int* __restrict__ qzeros,
    float* __restrict__ out)
{
    __shared__ bf16_t As[BMf * LDPF];
    __shared__ bf16_t Bs[BNf * LDPF];
    const int tid = threadIdx.x, lane = tid & 63, wid = tid >> 6;
    const int wr = wid >> 1, wc = wid & 1;
    const int m0 = blockIdx.y * BMf, n0 = blockIdx.x * BNf;
    const int a_row = tid >> 2, a_slot = tid & 3;
    const int b_k8l = tid >> 7, b_n = tid & 127;

    f32x4 acc[4][4];
    #pragma unroll
    for (int i = 0; i < 4; ++i)
        #pragma unroll
        for (int j = 0; j < 4; ++j) acc[i][j] = (f32x4)0.0f;

    for (int kt = 0; kt < IN_F / BKf; ++kt) {
        const int k0 = kt * BKf;
        const int g  = k0 >> 7;
        __syncthreads();
        #pragma unroll
        for (int p = 0; p < 2; ++p) {
            const int row = a_row + p * 64;
            const float* src = x + (size_t)(m0 + row) * IN_F + k0 + a_slot * 8;
            f32x4 v0 = *(const f32x4*)src;
            f32x4 v1 = *(const f32x4*)(src + 4);
            bf16x8 h;
            h[0]=(bf16_t)v0[0]; h[1]=(bf16_t)v0[1]; h[2]=(bf16_t)v0[2]; h[3]=(bf16_t)v0[3];
            h[4]=(bf16_t)v1[0]; h[5]=(bf16_t)v1[1]; h[6]=(bf16_t)v1[2]; h[7]=(bf16_t)v1[3];
            *(bf16x8*)(&As[row * LDPF + a_slot * 8]) = h;
        }
        {
            const int gn = n0 + b_n;
            const float s  = scales[(size_t)g * OUT_F + gn];
            const int   zw = qzeros[(size_t)g * (OUT_F / 8) + (gn >> 3)];
            const float sz = s * (float)(((zw >> ((gn & 7) * 4)) & 0xF) + 1);
            #pragma unroll
            for (int p = 0; p < 2; ++p) {
                const int k8l = b_k8l + p * 2;
                const int w = qweight[(size_t)(k0 / 8 + k8l) * OUT_F + gn];
                bf16x8 h;
                #pragma unroll
                for (int j = 0; j < 8; ++j)
                    h[j] = (bf16_t)fmaf((float)((w >> (4 * j)) & 0xF), s, -sz);
                *(bf16x8*)(&Bs[b_n * LDPF + k8l * 8]) = h;
            }
        }
        __syncthreads();
        bf16x8 af[4], bfr[4];
        #pragma unroll
        for (int m = 0; m < 4; ++m)
            af[m] = *(const bf16x8*)(&As[(wr * 64 + m * 16 + (lane & 15)) * LDPF + (lane >> 4) * 8]);
        #pragma unroll
        for (int n = 0; n < 4; ++n)
            bfr[n] = *(const bf16x8*)(&Bs[(wc * 64 + n * 16 + (lane & 15)) * LDPF + (lane >> 4) * 8]);
        #pragma unroll
        for (int m = 0; m < 4; ++m)
            #pragma unroll
            for (int n = 0; n < 4; ++n)
                acc[m][n] = __builtin_amdgcn_mfma_f32_16x16x32_bf16(af[m], bfr[n], acc[m][n], 0, 0, 0);
    }
    const int cn = lane & 15, cr4 = (lane >> 4) * 4;
    #pragma unroll
    for (int m = 0; m < 4; ++m)
        #pragma unroll
        for (int r = 0; r < 4; ++r) {
            const int grow = m0 + wr * 64 + m * 16 + cr4 + r;
            float* orow = out + (size_t)grow * OUT_F + n0 + wc * 64 + cn;
            #pragma unroll
            for (int n = 0; n < 4; ++n) orow[n * 16] = acc[m][n][r];
        }
}

extern "C" void kernel_launch(void* const* d_in, const int* in_sizes, int n_in,
                              void* d_out, int out_size, void* d_ws, size_t ws_size,
                              hipStream_t stream) {
    const float* x       = (const float*)d_in[0];
    const int*   qweight = (const int*)d_in[1];
    const float* scales  = (const float*)d_in[2];
    const int*   qzeros  = (const int*)d_in[3];
    float* out = (float*)d_out;

    const int M = in_sizes[0] / IN_F;                       // 8192
    const size_t xb_bytes = (size_t)M * IN_F * 2;           // 67 MB

    if (ws_size >= xb_bytes && (M % 256) == 0) {
        bf16_t* xb = (bf16_t*)d_ws;
        cvt_x_kernel<<<dim3((M * IN_F) / (256 * 8)), dim3(256), 0, stream>>>(x, xb);
        const int nwg = (OUT_F / 256) * (M / 256);          // 43*32 = 1376
        gemm_q4<<<dim3(nwg), dim3(512), 0, stream>>>(xb, qweight, scales, qzeros, out);
    } else {
        gptq_gemm_fused<<<dim3(OUT_F / BNf, M / BMf), dim3(256), 0, stream>>>(
            x, qweight, scales, qzeros, out);
    }
}

// Round 17
// 812.173 us; speedup vs baseline: 1.3817x; 1.0390x over previous
//
#include <hip/hip_runtime.h>
#include <hip/hip_bf16.h>

#define IN_F 4096
#define OUT_F 11008

typedef __bf16 bf16_t;
typedef _Float16 f16_t;
typedef f16_t f16x8 __attribute__((ext_vector_type(8)));
typedef f16_t f16x2 __attribute__((ext_vector_type(2)));
typedef u_int32_t u32;
typedef u32 u32x4 __attribute__((ext_vector_type(4)));
typedef bf16_t bf16x8 __attribute__((ext_vector_type(8)));
typedef float f32x4 __attribute__((ext_vector_type(4)));

// ============================ pass 1a: x f32 -> f16 ============================
__global__ __launch_bounds__(256) void cvt_x_kernel(const float* __restrict__ x,
                                                    f16_t* __restrict__ xb) {
    size_t i = ((size_t)blockIdx.x * 256 + threadIdx.x) * 8;
    f32x4 v0 = __builtin_nontemporal_load((const f32x4*)(x + i));
    f32x4 v1 = __builtin_nontemporal_load((const f32x4*)(x + i + 4));
    f16x8 h;
    h[0]=(f16_t)v0[0]; h[1]=(f16_t)v0[1]; h[2]=(f16_t)v0[2]; h[3]=(f16_t)v0[3];
    h[4]=(f16_t)v1[0]; h[5]=(f16_t)v1[1]; h[6]=(f16_t)v1[2]; h[7]=(f16_t)v1[3];
    *(f16x8*)(xb + i) = h;
}

// ========== pass 2: 256x256 8-phase GEMM, B raw-4-bit in LDS, f16 MFMA ==========
// R16 = R15's proven schedule/sync verbatim; numeric path moved to f16 with
// PACKED dequant (attacks R15's measured VALU bottleneck, 44% > MfmaUtil 35%):
//   per 2 elements: v_perm_b32 (gather nibble bytes) + v_and_or_b32
//   (mask|0x6400 -> f16 1024+q) + v_pk_add (sub exact packed 1025+z) +
//   v_pk_mul (x packed s) = 4 ops vs R15's ~6-7 with cvt chains.
//   q-z-1 integer-exact in f16; W rel-err ~2^-11 (better than bf16).
// MFMA: mfma_f32_16x16x32_f16 (same rate/layout as bf16; C/D layout
// dtype-independent). A path f32->f16 (exact-enough, |x|~N(0,1)).

#define NI (IN_F / 128)   // 32 iterations = 32 groups, 64 K-tiles

__global__ __launch_bounds__(512, 2) void gemm_q4(const f16_t* __restrict__ A,
                                                  const int* __restrict__ qweight,
                                                  const float* __restrict__ scales,
                                                  const int* __restrict__ qzeros,
                                                  float* __restrict__ C) {
    __shared__ __align__(16) f16_t smemA[2 * 2 * 128 * 64];   // 64 KiB
    __shared__ __align__(16) u32   smemB[2 * 2048];           // 16 KiB (4-bit B)

    const int tid  = threadIdx.x;
    const int lane = tid & 63;
    const int wid  = tid >> 6;      // 0..7
    const int wr   = wid >> 2;      // 0..1  (M half)
    const int wc   = wid & 3;       // 0..3  (N quarter)

    // bijective XCD swizzle: nwg = 1376 = 8*172
    const int bid = blockIdx.x;
    const int swz = (bid & 7) * 172 + (bid >> 3);
    const int bx = swz % 43;
    const int by = swz / 43;
    const int m0 = by * 256;
    const int n0 = bx * 256;

    // A staging map: linear LDS slot -> inverse-swizzled global position
    int lr0, kb0, lr1, kb1;
    {
        int L0 = tid * 16;
        int p0 = L0 ^ (((L0 >> 7) & 7) << 4);
        lr0 = p0 >> 7; kb0 = (p0 & 127) >> 1;
        int L1 = (512 + tid) * 16;
        int p1 = L1 ^ (((L1 >> 7) & 7) << 4);
        lr1 = p1 >> 7; kb1 = (p1 & 127) >> 1;
    }

    // A fragment-read swizzled column byte offsets within a 128B row
    const int xm = (lane & 7) << 4;
    const int arow = lane & 15;
    int colk[2];
    #pragma unroll
    for (int ks = 0; ks < 2; ++ks)
        colk[ks] = ((ks * 64) + ((lane >> 4) * 16)) ^ xm;

    // B-side: per-lane LDS word base; per-thread stage source pointer
    const int ncol = n0 + wc * 64 + (lane & 15);
    const u32* bw = smemB + (wc * 512 + (lane >> 4) * 16 + (lane & 15));
    const int kwS  = (tid >> 2) & 7;
    const int colS = (tid >> 5) * 16 + (tid & 3) * 4;
    const u32* qB = (const u32*)qweight + (size_t)kwS * OUT_F + n0 + colS;
    const int zsh = (lane & 7) * 4;

#define STAGE_A(buf, half, koff)                                                           \
    do {                                                                                   \
        const f16_t* g0_ = A + (size_t)(m0 + (half) * 128 + lr0) * IN_F + (koff) + kb0;    \
        __builtin_amdgcn_global_load_lds(                                                  \
            (const __attribute__((address_space(1))) u32*)g0_,                             \
            (__attribute__((address_space(3))) u32*)((char*)smemA + (buf) * 32768 +        \
                                                     (half) * 16384 + wid * 1024),         \
            16, 0, 0);                                                                     \
        const f16_t* g1_ = A + (size_t)(m0 + (half) * 128 + lr1) * IN_F + (koff) + kb1;    \
        __builtin_amdgcn_global_load_lds(                                                  \
            (const __attribute__((address_space(1))) u32*)g1_,                             \
            (__attribute__((address_space(3))) u32*)((char*)smemA + (buf) * 32768 +        \
                                                     (half) * 16384 + 8192 + wid * 1024),  \
            16, 0, 0);                                                                     \
    } while (0)

// B stage: one width-16 load/thread; dest linear; src = qweight row (ktrow+kwS)
#define STAGE_B(buf, ktrow)                                                                \
    __builtin_amdgcn_global_load_lds(                                                      \
        (const __attribute__((address_space(1))) u32*)(qB + (size_t)(ktrow) * OUT_F),      \
        (__attribute__((address_space(3))) u32*)((char*)smemB + (buf) * 8192 + tid * 16),  \
        16, 0, 0)

// 8 ds_read_b128 -> aR : A fragments (4 m-tiles x 2 k-slices)
#define RD_A(dst, buf, mbase)                                                              \
    _Pragma("unroll") for (int mm = 0; mm < 4; ++mm)                                       \
    _Pragma("unroll") for (int ks = 0; ks < 2; ++ks)                                       \
        dst[mm * 2 + ks] = *(const f16x8*)((const char*)smemA + (buf) * 32768 +            \
            wr * 16384 + (((mbase) + mm) * 16 + arow) * 128 + colk[ks]);

// 8 ds_read_b32 (base + compile-time imm): all 4 n-tiles x 2 ks of one buffer
#define RD_W(buf)                                                                          \
    _Pragma("unroll") for (int nt = 0; nt < 4; ++nt)                                       \
    _Pragma("unroll") for (int ks = 0; ks < 2; ++ks)                                       \
        w[nt * 2 + ks] = bw[(buf) * 2048 + nt * 128 + ks * 64];

// packed-f16 dequant: one B pair (n-tiles nt0..nt0+1, 2 ks)
// per pair-word: perm + and_or + pk_sub + pk_mul = 4 VALU / 2 elements
#define DEQ(dst, nt0)                                                                      \
    _Pragma("unroll") for (int nn = 0; nn < 2; ++nn)                                       \
    _Pragma("unroll") for (int ks = 0; ks < 2; ++ks) {                                     \
        const u32 wv_ = w[((nt0) + nn) * 2 + ks];                                          \
        const u32 od_ = wv_ >> 4;                                                          \
        const f16x2 zp_ = zh[(nt0) + nn];                                                  \
        const f16x2 sp_ = sh[(nt0) + nn];                                                  \
        u32x4 hw_;                                                                         \
        _Pragma("unroll") for (int p = 0; p < 4; ++p) {                                    \
            u32 t_ = __builtin_amdgcn_perm(od_, wv_,                                       \
                         0x0C000C00u | (u32)p | ((u32)(4 + p) << 16));                     \
            u32 u_ = (t_ & 0x000F000Fu) | 0x64006400u;                                     \
            f16x2 b_ = (__builtin_bit_cast(f16x2, u_) - zp_) * sp_;                        \
            hw_[p] = __builtin_bit_cast(u32, b_);                                          \
        }                                                                                  \
        dst[nn * 2 + ks] = __builtin_bit_cast(f16x8, hw_);                                 \
    }

// 16 MFMA: one quadrant (4 m x 2 n x 2 ks)
#define MFMA_Q(aArr, bArr, mbase, nbase)                                                   \
    __builtin_amdgcn_s_setprio(1);                                                         \
    _Pragma("unroll") for (int mm = 0; mm < 4; ++mm)                                       \
    _Pragma("unroll") for (int nn = 0; nn < 2; ++nn)                                       \
    _Pragma("unroll") for (int ks = 0; ks < 2; ++ks)                                       \
        acc[(mbase) + mm][(nbase) + nn] = __builtin_amdgcn_mfma_f32_16x16x32_f16(          \
            aArr[mm * 2 + ks], bArr[nn * 2 + ks], acc[(mbase) + mm][(nbase) + nn],         \
            0, 0, 0);                                                                      \
    __builtin_amdgcn_s_setprio(0);

// per-group packed constants: zh = f16x2(1025+z), sh = f16x2(s)
#define CVT_SCALES()                                                                       \
    _Pragma("unroll") for (int nt = 0; nt < 4; ++nt) {                                     \
        u32 zb_ = 0x6401u + ((zraw[nt] >> zsh) & 0xFu);                                    \
        zb_ |= zb_ << 16;                                                                  \
        zh[nt] = __builtin_bit_cast(f16x2, zb_);                                           \
        u32 sb_ = (u32)__builtin_bit_cast(unsigned short, (f16_t)sraw[nt]);                \
        sb_ |= sb_ << 16;                                                                  \
        sh[nt] = __builtin_bit_cast(f16x2, sb_);                                           \
    }

#define SCHED0() __builtin_amdgcn_sched_barrier(0)
#define BAR() do { SCHED0(); __builtin_amdgcn_s_barrier(); } while (0)
#define VMCNT10() asm volatile("s_waitcnt vmcnt(10)" ::: "memory")
#define VMCNT2()  asm volatile("s_waitcnt vmcnt(2)"  ::: "memory")
#define VMCNT0()  asm volatile("s_waitcnt vmcnt(0)"  ::: "memory")

    f32x4 acc[8][4];
    #pragma unroll
    for (int m = 0; m < 8; ++m)
        #pragma unroll
        for (int n = 0; n < 4; ++n)
            acc[m][n] = (f32x4)0.0f;

    f16x8 aR[8], b01[4], b23[4];
    u32   w[8];
    f16x2 zh[4], sh[4];
    float sraw[4]; u32 zraw[4];

    // ---- prologue: stage A-buf0(T0), B-buf0(T0), B-buf1(T1), A10(T1);
    //      drain ALL (one-time, order-robust); scales group 0; deq T0 pairs;
    //      barrier so ph1's STAGE_B can't overwrite B-buf0 under readers.
    STAGE_A(0, 0, 0); STAGE_A(0, 1, 0);
    STAGE_B(0, 0);
    STAGE_B(1, 8);
    STAGE_A(1, 0, 64);
    VMCNT0();
    BAR();
    #pragma unroll
    for (int nt = 0; nt < 4; ++nt) {
        sraw[nt] = scales[ncol + nt * 16];
        zraw[nt] = ((const u32*)qzeros)[(ncol >> 3) + nt * 2];
    }
    CVT_SCALES();
    RD_W(0);
    DEQ(b01, 0);
    DEQ(b23, 2);
    BAR();   // kills the prologue->ph1 B-buf0 WAR race

    for (int i = 0; i < NI; ++i) {
        const int  kc = i * 128;        // T0 in buf0; T1 = kc+64 in buf1
        const int  kn = kc + 128;       // T2 in buf0; T3 = kn+64 in buf1
        const bool nl = (i + 1 < NI);

        // ph1: reads A(M0,buf0); stage A11(T1), B-buf0(T2); MFMA(M0,N01)
        RD_A(aR, 0, 0);
        STAGE_A(1, 1, kc + 64);
        if (nl) STAGE_B(0, (kn) >> 3);
        MFMA_Q(aR, b01, 0, 0);
        BAR();
        // ph2: scale raws for group i+1 (confined here); MFMA(M0,N23)
        if (nl) {
            #pragma unroll
            for (int nt = 0; nt < 4; ++nt) {
                sraw[nt] = scales[ncol + (i + 1) * OUT_F + nt * 16];
                zraw[nt] = ((const u32*)qzeros)[(ncol >> 3) + (i + 1) * (OUT_F / 8) + nt * 2];
            }
        }
        MFMA_Q(aR, b23, 0, 2);
        BAR();
        // ph3: reads A(M1,buf0); MFMA(M1,N01)
        RD_A(aR, 0, 4);
        MFMA_Q(aR, b01, 4, 0);
        BAR();
        // ph4: stage A00(T2); MFMA(M1,N23); vmcnt(10) -> T1-A complete
        //      (drains entering A10 + all of ph1; keeps sc8+A00); deq T1 pairs
        if (nl) STAGE_A(0, 0, kn);
        MFMA_Q(aR, b23, 4, 2);
        if (nl) VMCNT10(); else VMCNT0();
        RD_W(1);
        DEQ(b01, 0);
        DEQ(b23, 2);
        BAR();
        // ph5: reads A(M0,buf1); stage A01(T2), B-buf1(T3); MFMA(M0,N01)
        RD_A(aR, 1, 0);
        if (nl) { STAGE_A(0, 1, kn); STAGE_B(1, (kn + 64) >> 3); }
        MFMA_Q(aR, b01, 0, 0);
        BAR();
        // ph6: MFMA(M0,N23)
        MFMA_Q(aR, b23, 0, 2);
        BAR();
        // ph7: reads A(M1,buf1); convert group-(i+1) packed scales; MFMA(M1,N01)
        RD_A(aR, 1, 4);
        if (nl) CVT_SCALES();
        MFMA_Q(aR, b01, 4, 0);
        BAR();
        // ph8: stage A10(T3); MFMA(M1,N23); vmcnt(2) keeps only A10(T3):
        //      T2's A00/A01/B0 all published; w-reads after the wait;
        //      deq T2 pairs (group i+1 scales)
        if (nl) STAGE_A(1, 0, kn + 64);
        MFMA_Q(aR, b23, 4, 2);
        if (nl) VMCNT2(); else VMCNT0();
        if (nl) {
            RD_W(0);
            DEQ(b01, 0);
            DEQ(b23, 2);
        }
        BAR();
    }

    // epilogue: C/D layout col = lane&15, row = (lane>>4)*4 + r
    const int cn  = lane & 15;
    const int cr4 = (lane >> 4) * 4;
    #pragma unroll
    for (int m = 0; m < 8; ++m) {
        #pragma unroll
        for (int r = 0; r < 4; ++r) {
            const int grow = m0 + wr * 128 + m * 16 + cr4 + r;
            float* orow = C + (size_t)grow * OUT_F + n0 + wc * 64 + cn;
            #pragma unroll
            for (int n = 0; n < 4; ++n)
                orow[n * 16] = acc[m][n][r];
        }
    }
}

// ===================== fallback: fused kernel (R0 structure) =====================
#define BMf 128
#define BNf 128
#define BKf 32
#define LDPF 40

__global__ __launch_bounds__(256, 2) void gptq_gemm_fused(
    const float* __restrict__ x, const int* __restrict__ qweight,
    const float* __restrict__ scales, const int* __restrict__ qzeros,
    float* __restrict__ out)
{
    __shared__ bf16_t As[BMf * LDPF];
    __shared__ bf16_t Bs[BNf * LDPF];
    const int tid = threadIdx.x, lane = tid & 63, wid = tid >> 6;
    const int wr = wid >> 1, wc = wid & 1;
    const int m0 = blockIdx.y * BMf, n0 = blockIdx.x * BNf;
    const int a_row = tid >> 2, a_slot = tid & 3;
    const int b_k8l = tid >> 7, b_n = tid & 127;

    f32x4 acc[4][4];
    #pragma unroll
    for (int i = 0; i < 4; ++i)
        #pragma unroll
        for (int j = 0; j < 4; ++j) acc[i][j] = (f32x4)0.0f;

    for (int kt = 0; kt < IN_F / BKf; ++kt) {
        const int k0 = kt * BKf;
        const int g  = k0 >> 7;
        __syncthreads();
        #pragma unroll
        for (int p = 0; p < 2; ++p) {
            const int row = a_row + p * 64;
            const float* src = x + (size_t)(m0 + row) * IN_F + k0 + a_slot * 8;
            f32x4 v0 = *(const f32x4*)src;
            f32x4 v1 = *(const f32x4*)(src + 4);
            bf16x8 h;
            h[0]=(bf16_t)v0[0]; h[1]=(bf16_t)v0[1]; h[2]=(bf16_t)v0[2]; h[3]=(bf16_t)v0[3];
            h[4]=(bf16_t)v1[0]; h[5]=(bf16_t)v1[1]; h[6]=(bf16_t)v1[2]; h[7]=(bf16_t)v1[3];
            *(bf16x8*)(&As[row * LDPF + a_slot * 8]) = h;
        }
        {
            const int gn = n0 + b_n;
            const float s  = scales[(size_t)g * OUT_F + gn];
            const int   zw = qzeros[(size_t)g * (OUT_F / 8) + (gn >> 3)];
            const float sz = s * (float)(((zw >> ((gn & 7) * 4)) & 0xF) + 1);
            #pragma unroll
            for (int p = 0; p < 2; ++p) {
                const int k8l = b_k8l + p * 2;
                const int w = qweight[(size_t)(k0 / 8 + k8l) * OUT_F + gn];
                bf16x8 h;
                #pragma unroll
                for (int j = 0; j < 8; ++j)
                    h[j] = (bf16_t)fmaf((float)((w >> (4 * j)) & 0xF), s, -sz);
                *(bf16x8*)(&Bs[b_n * LDPF + k8l * 8]) = h;
            }
        }
        __syncthreads();
        bf16x8 af[4], bfr[4];
        #pragma unroll
        for (int m = 0; m < 4; ++m)
            af[m] = *(const bf16x8*)(&As[(wr * 64 + m * 16 + (lane & 15)) * LDPF + (lane >> 4) * 8]);
        #pragma unroll
        for (int n = 0; n < 4; ++n)
            bfr[n] = *(const bf16x8*)(&Bs[(wc * 64 + n * 16 + (lane & 15)) * LDPF + (lane >> 4) * 8]);
        #pragma unroll
        for (int m = 0; m < 4; ++m)
            #pragma unroll
            for (int n = 0; n < 4; ++n)
                acc[m][n] = __builtin_amdgcn_mfma_f32_16x16x32_bf16(af[m], bfr[n], acc[m][n], 0, 0, 0);
    }
    const int cn = lane & 15, cr4 = (lane >> 4) * 4;
    #pragma unroll
    for (int m = 0; m < 4; ++m)
        #pragma unroll
        for (int r = 0; r < 4; ++r) {
            const int grow = m0 + wr * 64 + m * 16 + cr4 + r;
            float* orow = out + (size_t)grow * OUT_F + n0 + wc * 64 + cn;
            #pragma unroll
            for (int n = 0; n < 4; ++n) orow[n * 16] = acc[m][n][r];
        }
}

extern "C" void kernel_launch(void* const* d_in, const int* in_sizes, int n_in,
                              void* d_out, int out_size, void* d_ws, size_t ws_size,
                              hipStream_t stream) {
    const float* x       = (const float*)d_in[0];
    const int*   qweight = (const int*)d_in[1];
    const float* scales  = (const float*)d_in[2];
    const int*   qzeros  = (const int*)d_in[3];
    float* out = (float*)d_out;

    const int M = in_sizes[0] / IN_F;                       // 8192
    const size_t xb_bytes = (size_t)M * IN_F * 2;           // 67 MB

    if (ws_size >= xb_bytes && (M % 256) == 0) {
        f16_t* xb = (f16_t*)d_ws;
        cvt_x_kernel<<<dim3((M * IN_F) / (256 * 8)), dim3(256), 0, stream>>>(x, xb);
        const int nwg = (OUT_F / 256) * (M / 256);          // 43*32 = 1376
        gemm_q4<<<dim3(nwg), dim3(512), 0, stream>>>(xb, qweight, scales, qzeros, out);
    } else {
        gptq_gemm_fused<<<dim3(OUT_F / BNf, M / BMf), dim3(256), 0, stream>>>(
            x, qweight, scales, qzeros, out);
    }
}